// Round 2
// baseline (39134.195 us; speedup 1.0000x reference)
//
#include <hip/hip_runtime.h>

// LSTMRecursiveModel: B=16, L=96, H=256, NL=2, O=32.
// 3168 sequential LSTM steps. Cooperative persistent kernel, 1 grid barrier per
// step (software-pipelined: phase p computes L0(step p) || L1(step p-1)).
// Weights persistent in LDS, distributed over 96 WGs:
//   WG 0..31  : layer0, 8 h-columns each (32 rows of Whh0, 34.8KB LDS)
//   WG 32..95 : layer1, 4 h-columns each (16 Wih1 rows + 16 Whh1 rows)
// Cell state c kept in registers (double precision) of the owning lane.
// h exchanged via d_ws.
//
// Round 1 change: precise activations (expf/tanhf instead of __expf-based
// fast approximations) + double-precision cell state. The autoregressive
// feedback loop amplifies per-step error ~1.3-1.4x per window iteration
// (x32), so activation error must stay at the fp32 ulp noise floor.

#define NWG 96
#define LASTP 3169   // phases p = 0..3169; L0 active p<=3167, L1 active 1<=p<=3168

__device__ __forceinline__ float sigm(float x) { return 1.0f / (1.0f + expf(-x)); }

// ws layout (floats):
//   h0buf : [2][16][256] at 0      (double-buffered by step parity)
//   h1buf : [2][16][256] at 8192
//   predbuf: [32][16]    at 16384
//   barrier: 2 uints     at 17024
__global__ void init_kernel(float* __restrict__ out, float* __restrict__ ws) {
  int i = blockIdx.x * blockDim.x + threadIdx.x;
  if (i < 16 * 96) out[i] = 0.0f;
  for (int j = i; j < 17056; j += gridDim.x * blockDim.x) ws[j] = 0.0f;
}

__global__ __launch_bounds__(256, 1) void lstm_coop(
    const float* __restrict__ x_enc,
    const float* __restrict__ Wih0, const float* __restrict__ Whh0,
    const float* __restrict__ bih0, const float* __restrict__ bhh0,
    const float* __restrict__ Wih1, const float* __restrict__ Whh1,
    const float* __restrict__ bih1, const float* __restrict__ bhh1,
    const float* __restrict__ fc_w, const float* __restrict__ fc_b,
    float* __restrict__ out, float* __restrict__ ws) {
  const int w = blockIdx.x;
  const int tid = threadIdx.x;
  const int wave = tid >> 6, lane = tid & 63;
  const int b = lane & 15, q = lane >> 4;   // batch, k-segment (64 k each)

  float* h0buf = ws;
  float* h1buf = ws + 8192;
  float* predbuf = ws + 16384;
  unsigned* bar = (unsigned*)(ws + 17024);

  // 32 rows x (4 segs x 68 floats) : addr = R*272 + q*68 + j.
  // Bank of float4 base = (16R + 4q + 4jj) & 31 -> the 4 q-addresses per
  // wave-instruction hit disjoint banks; 16 same-address lanes broadcast.
  __shared__ float wlds[32 * 272];

  const bool isL0 = (w < 32);
  const int u = w - 32;

  // ---- stage weights into LDS (row i, k = tid : coalesced 1KB rows) ----
  if (isL0) {
    for (int i = 0; i < 32; ++i) {
      int r_w = i & 7, wv = i >> 3;
      int col = w * 8 + wv * 2 + (r_w >> 2), gate = r_w & 3;
      wlds[i * 272 + (tid >> 6) * 68 + (tid & 63)] = Whh0[(gate * 256 + col) * 256 + tid];
    }
  } else {
    for (int i = 0; i < 32; ++i) {
      int r_w = i & 7, wv = i >> 3;
      int col = u * 4 + wv, gate = r_w & 3;
      const float* Wsrc = (r_w >> 2) ? Whh1 : Wih1;
      wlds[i * 272 + (tid >> 6) * 68 + (tid & 63)] = Wsrc[(gate * 256 + col) * 256 + tid];
    }
  }

  // ---- per-lane constants ----
  float biasv[8], xw[8];
  if (isL0) {
#pragma unroll
    for (int r = 0; r < 8; ++r) {
      int col = w * 8 + wave * 2 + (r >> 2), gate = r & 3;
      int grow = gate * 256 + col;
      biasv[r] = bih0[grow] + bhh0[grow];
      xw[r] = Wih0[grow];   // Wih0 is (1024,1): scalar x-weight per gate row
    }
  } else {
#pragma unroll
    for (int g = 0; g < 4; ++g) {
      int col = u * 4 + wave;
      int grow = g * 256 + col;
      biasv[g] = bih1[grow] + bhh1[grow];
      xw[g] = 0.0f;
    }
#pragma unroll
    for (int g = 4; g < 8; ++g) { biasv[g] = 0.0f; xw[g] = 0.0f; }
  }
  __syncthreads();

  double c0a = 0.0, c0b = 0.0, c1 = 0.0;   // cell states (valid on q==0 lanes)
  const int colBaseL0 = w * 8 + wave * 2;   // L0 wave owns 2 columns
  const int colL1 = u * 4 + wave;           // L1 wave owns 1 column

  for (int p = 0; p <= LASTP; ++p) {
    if (isL0) {
      if (p <= 3167) {
        // ---- layer 0, step p: gates = x*wih0 + h0 @ Whh0^T + bias ----
        const float* hsrc = h0buf + ((p + 1) & 1) * 4096 + b * 256 + q * 64;
        float h[64];
#pragma unroll
        for (int jj = 0; jj < 16; ++jj) {
          float4 v = *(const float4*)(hsrc + jj * 4);
          h[jj * 4 + 0] = v.x; h[jj * 4 + 1] = v.y; h[jj * 4 + 2] = v.z; h[jj * 4 + 3] = v.w;
        }
        float acc[8];
#pragma unroll
        for (int r = 0; r < 8; ++r) acc[r] = 0.0f;
#pragma unroll
        for (int r = 0; r < 8; ++r) {
          int base = (wave * 8 + r) * 272 + q * 68;
#pragma unroll
          for (int jj = 0; jj < 16; ++jj) {
            float4 wv = *(const float4*)&wlds[base + jj * 4];
            acc[r] += wv.x * h[jj * 4] + wv.y * h[jj * 4 + 1] + wv.z * h[jj * 4 + 2] + wv.w * h[jj * 4 + 3];
          }
        }
#pragma unroll
        for (int r = 0; r < 8; ++r) {
          acc[r] += __shfl_xor(acc[r], 16);
          acc[r] += __shfl_xor(acc[r], 32);
        }
        if (q == 0) {
          float xv;
          {
            int s = p;
            if (s < 96) {
              xv = x_enc[b * 96 + s];
            } else {
              int sk = s - 96;
              int k = sk / 96;
              int t = sk - k * 96;
              xv = (t < 96 - k) ? x_enc[b * 96 + k + t] : predbuf[(t - 96 + k) * 16 + b];
            }
          }
          float hv0, hv1;
          {
            float gi = acc[0] + xv * xw[0] + biasv[0];
            float gf = acc[1] + xv * xw[1] + biasv[1];
            float gg = acc[2] + xv * xw[2] + biasv[2];
            float go = acc[3] + xv * xw[3] + biasv[3];
            double cn = (double)sigm(gf) * c0a + (double)(sigm(gi) * tanhf(gg));
            hv0 = sigm(go) * tanhf((float)cn);
            c0a = cn;
          }
          {
            float gi = acc[4] + xv * xw[4] + biasv[4];
            float gf = acc[5] + xv * xw[5] + biasv[5];
            float gg = acc[6] + xv * xw[6] + biasv[6];
            float go = acc[7] + xv * xw[7] + biasv[7];
            double cn = (double)sigm(gf) * c0b + (double)(sigm(gi) * tanhf(gg));
            hv1 = sigm(go) * tanhf((float)cn);
            c0b = cn;
          }
          *(float2*)(h0buf + (p & 1) * 4096 + b * 256 + colBaseL0) = make_float2(hv0, hv1);
        }
      }
      // ---- prediction (one phase after h1(s) lands; s=191+96*jp is odd) ----
      if (w == 0 && wave == 0 && p >= 193 && ((p - 193) % 96) == 0) {
        int jp = (p - 193) / 96;
        if (jp < 32) {
          const float* hsrc = h1buf + 4096 + b * 256 + q * 64;  // parity 1 always
          const float* fw = fc_w + q * 64;
          float acc = 0.0f;
#pragma unroll
          for (int jj = 0; jj < 16; ++jj) {
            float4 hv = *(const float4*)(hsrc + jj * 4);
            float4 wv = *(const float4*)(fw + jj * 4);
            acc += hv.x * wv.x + hv.y * wv.y + hv.z * wv.z + hv.w * wv.w;
          }
          acc += __shfl_xor(acc, 16);
          acc += __shfl_xor(acc, 32);
          if (q == 0) {
            float pv = acc + fc_b[0];
            predbuf[jp * 16 + b] = pv;
            out[b * 96 + jp] = pv;
          }
        }
      }
    } else {
      if (p >= 1 && p <= 3168) {
        // ---- layer 1, step s=p-1: gates = h0'(s) @ Wih1^T + h1(s-1) @ Whh1^T + bias ----
        const float* h0src = h0buf + ((p + 1) & 1) * 4096 + b * 256 + q * 64;
        const float* h1src = h1buf + (p & 1) * 4096 + b * 256 + q * 64;
        float ha[64], hb[64];
#pragma unroll
        for (int jj = 0; jj < 16; ++jj) {
          float4 v = *(const float4*)(h0src + jj * 4);
          ha[jj * 4 + 0] = v.x; ha[jj * 4 + 1] = v.y; ha[jj * 4 + 2] = v.z; ha[jj * 4 + 3] = v.w;
        }
#pragma unroll
        for (int jj = 0; jj < 16; ++jj) {
          float4 v = *(const float4*)(h1src + jj * 4);
          hb[jj * 4 + 0] = v.x; hb[jj * 4 + 1] = v.y; hb[jj * 4 + 2] = v.z; hb[jj * 4 + 3] = v.w;
        }
        float acc[8];
#pragma unroll
        for (int r = 0; r < 8; ++r) acc[r] = 0.0f;
#pragma unroll
        for (int r = 0; r < 4; ++r) {   // Wih1 rows (input = h0')
          int base = (wave * 8 + r) * 272 + q * 68;
#pragma unroll
          for (int jj = 0; jj < 16; ++jj) {
            float4 wv = *(const float4*)&wlds[base + jj * 4];
            acc[r] += wv.x * ha[jj * 4] + wv.y * ha[jj * 4 + 1] + wv.z * ha[jj * 4 + 2] + wv.w * ha[jj * 4 + 3];
          }
        }
#pragma unroll
        for (int r = 4; r < 8; ++r) {   // Whh1 rows (input = h1)
          int base = (wave * 8 + r) * 272 + q * 68;
#pragma unroll
          for (int jj = 0; jj < 16; ++jj) {
            float4 wv = *(const float4*)&wlds[base + jj * 4];
            acc[r] += wv.x * hb[jj * 4] + wv.y * hb[jj * 4 + 1] + wv.z * hb[jj * 4 + 2] + wv.w * hb[jj * 4 + 3];
          }
        }
#pragma unroll
        for (int r = 0; r < 8; ++r) {
          acc[r] += __shfl_xor(acc[r], 16);
          acc[r] += __shfl_xor(acc[r], 32);
        }
        if (q == 0) {
          float gi = acc[0] + acc[4] + biasv[0];
          float gf = acc[1] + acc[5] + biasv[1];
          float gg = acc[2] + acc[6] + biasv[2];
          float go = acc[3] + acc[7] + biasv[3];
          double cn = (double)sigm(gf) * c1 + (double)(sigm(gi) * tanhf(gg));
          float hn = sigm(go) * tanhf((float)cn);
          c1 = cn;
          h1buf[((p + 1) & 1) * 4096 + b * 256 + colL1] = hn;
        }
      }
    }

    // ---- grid barrier (sense via monotone generation counter) ----
    __syncthreads();   // drains each wave's global stores (vmcnt) before signal
    if (tid == 0) {
      unsigned arrived = __hip_atomic_fetch_add(&bar[0], 1u, __ATOMIC_ACQ_REL, __HIP_MEMORY_SCOPE_AGENT);
      if (arrived == NWG - 1) {
        __hip_atomic_store(&bar[0], 0u, __ATOMIC_RELAXED, __HIP_MEMORY_SCOPE_AGENT);
        __hip_atomic_store(&bar[1], (unsigned)(p + 1), __ATOMIC_RELEASE, __HIP_MEMORY_SCOPE_AGENT);
      } else {
        while (__hip_atomic_load(&bar[1], __ATOMIC_RELAXED, __HIP_MEMORY_SCOPE_AGENT) < (unsigned)(p + 1)) {}
        __threadfence();   // acquire: invalidate stale lines before next phase reads
      }
    }
    __syncthreads();
  }
}

extern "C" void kernel_launch(void* const* d_in, const int* in_sizes, int n_in,
                              void* d_out, int out_size, void* d_ws, size_t ws_size,
                              hipStream_t stream) {
  const float* x_enc = (const float*)d_in[0];
  const float* Wih0 = (const float*)d_in[4];
  const float* Whh0 = (const float*)d_in[5];
  const float* bih0 = (const float*)d_in[6];
  const float* bhh0 = (const float*)d_in[7];
  const float* Wih1 = (const float*)d_in[8];
  const float* Whh1 = (const float*)d_in[9];
  const float* bih1 = (const float*)d_in[10];
  const float* bhh1 = (const float*)d_in[11];
  const float* fc_w = (const float*)d_in[12];
  const float* fc_b = (const float*)d_in[13];
  float* out = (float*)d_out;
  float* ws = (float*)d_ws;

  hipLaunchKernelGGL(init_kernel, dim3(8), dim3(256), 0, stream, out, ws);

  void* args[] = {&x_enc, &Wih0, &Whh0, &bih0, &bhh0, &Wih1, &Whh1, &bih1, &bhh1,
                  &fc_w, &fc_b, &out, &ws};
  (void)hipLaunchCooperativeKernel((void*)lstm_coop, dim3(NWG), dim3(256), args, 0u, stream);
}